// Round 1
// baseline (194.832 us; speedup 1.0000x reference)
//
#include <hip/hip_runtime.h>
#include <stdint.h>

#define DCOLS 16384
#define TPB 256
#define PER 64     // DCOLS / TPB elements per thread
#define NB 17      // histogram bins (boundaries)
#define CAP 256    // candidate capacity (== TPB, one LDS slot per thread)

// Histogram boundaries around the expected 64th-of-16384 N(0,1) order stat (~2.66).
__device__ __constant__ float BNDS[NB] = {
    2.30f, 2.35f, 2.40f, 2.45f, 2.50f, 2.55f, 2.60f, 2.65f,
    2.70f, 2.75f, 2.80f, 2.85f, 2.90f, 2.95f, 3.00f, 3.05f, 3.10f};

// Monotone bijection float -> uint32 (order-preserving for all non-NaN).
__device__ __forceinline__ uint32_t f2k(float f) {
  uint32_t u = __float_as_uint(f);
  return (u & 0x80000000u) ? ~u : (u | 0x80000000u);
}
__device__ __forceinline__ float k2f(uint32_t kv) {
  uint32_t u = (kv & 0x80000000u) ? (kv ^ 0x80000000u) : ~kv;
  return __uint_as_float(u);
}

__global__ void __launch_bounds__(TPB) topk_mask_kernel(
    const float* __restrict__ x, const int* __restrict__ kptr,
    float* __restrict__ out) {
  const int tid = threadIdx.x;
  const unsigned k = (unsigned)(*kptr);
  const size_t rowoff = (size_t)blockIdx.x * (size_t)DCOLS;
  const float4* xr = reinterpret_cast<const float4*>(x + rowoff);
  float4* outr = reinterpret_cast<float4*>(out + rowoff);

  __shared__ unsigned hist[NB];
  __shared__ unsigned bc[4];  // loKey, hiKey, gLo, gHi
  __shared__ unsigned scnt;
  __shared__ unsigned long long sv[CAP];

  if (tid < NB) hist[tid] = 0u;
  __syncthreads();

  // ---- Load row into registers as keys; histogram the (2.3, inf) tail ----
  uint32_t kk[PER];
#pragma unroll
  for (int i = 0; i < PER / 4; ++i) {
    float4 v = xr[tid + TPB * i];
#pragma unroll
    for (int c = 0; c < 4; ++c) {
      float f = (c == 0) ? v.x : (c == 1) ? v.y : (c == 2) ? v.z : v.w;
      kk[4 * i + c] = f2k(f);
      if (f > BNDS[0]) {
        int b = 0;
#pragma unroll
        for (int j = 1; j < NB; ++j) b += (f > BNDS[j]) ? 1 : 0;
        atomicAdd(&hist[b], 1u);
      }
    }
  }
  __syncthreads();

  // ---- Thread 0: pick bracket (lo, hi] with g(lo) >= k > g(hi) ----
  if (tid == 0) {
    unsigned gnext = 0;  // g_{j+1}
    unsigned gj = 0;
    int jstar = -1;
    for (int j = NB - 1; j >= 0; --j) {
      gj = gnext + hist[j];
      if (gj >= k) { jstar = j; break; }
      gnext = gj;
    }
    if (jstar < 0) {
      // k-th largest is below BNDS[0]: bracket (0, key(BNDS[0])], refine by bisection
      bc[0] = 0u; bc[1] = f2k(BNDS[0]); bc[2] = (unsigned)DCOLS; bc[3] = gnext;
    } else if (jstar == NB - 1) {
      bc[0] = f2k(BNDS[NB - 1]); bc[1] = 0xFFFFFFFFu; bc[2] = gj; bc[3] = 0u;
    } else {
      bc[0] = f2k(BNDS[jstar]); bc[1] = f2k(BNDS[jstar + 1]); bc[2] = gj; bc[3] = gnext;
    }
  }
  __syncthreads();
  unsigned lo = bc[0], hi = bc[1], glo = bc[2], ghi = bc[3];

  // ---- Bisection fallback: shrink bracket until candidates fit in CAP ----
  int guard = 0;
  while ((glo - ghi) > (unsigned)CAP && (hi - lo) > 1u && guard < 40) {
    unsigned mid = lo + ((hi - lo) >> 1);
    if (tid == 0) scnt = 0u;
    __syncthreads();
    unsigned c = 0;
#pragma unroll
    for (int i = 0; i < PER; ++i) c += (kk[i] > mid) ? 1u : 0u;
#pragma unroll
    for (int off = 32; off > 0; off >>= 1) c += __shfl_down(c, off);
    if ((tid & 63) == 0) atomicAdd(&scnt, c);
    __syncthreads();
    unsigned gm = scnt;
    __syncthreads();  // all reads of scnt done before next iter's reset
    if (gm >= k) { lo = mid; glo = gm; } else { hi = mid; ghi = gm; }
    ++guard;
  }

  // ---- Compact candidates (lo, hi] into LDS as 64-bit sortvals ----
  sv[tid] = 0ull;
  if (tid == 0) scnt = 0u;
  __syncthreads();
#pragma unroll
  for (int i = 0; i < PER; ++i) {
    uint32_t kv = kk[i];
    if (kv > lo && kv <= hi) {
      unsigned pos = atomicAdd(&scnt, 1u);
      if (pos < CAP) {
        unsigned j = 4u * (unsigned)tid + 1024u * (unsigned)(i >> 2) + (unsigned)(i & 3);
        sv[pos] = ((unsigned long long)kv << 32) |
                  (unsigned long long)(0xFFFFFFFFu - j);  // lower index -> larger sv
      }
    }
  }
  __syncthreads();

  // ---- Bitonic sort ascending, 256 elements, 256 threads ----
  for (int size = 2; size <= CAP; size <<= 1) {
    for (int stride = size >> 1; stride > 0; stride >>= 1) {
      int ixj = tid ^ stride;
      if (ixj > tid) {
        unsigned long long a = sv[tid], b2 = sv[ixj];
        bool up = ((tid & size) == 0);
        if ((a > b2) == up) { sv[tid] = b2; sv[ixj] = a; }
      }
      __syncthreads();
    }
  }

  const unsigned r = k - ghi;  // rank among candidates, 1-based; 1 <= r <= CAP
  const unsigned long long thr = sv[CAP - r];

  // ---- Write output from registers ----
#pragma unroll
  for (int i = 0; i < PER / 4; ++i) {
    float4 o;
#pragma unroll
    for (int c = 0; c < 4; ++c) {
      const int idx = 4 * i + c;
      const uint32_t kv = kk[idx];
      const unsigned j = 4u * (unsigned)tid + 1024u * (unsigned)i + (unsigned)c;
      const unsigned long long s =
          ((unsigned long long)kv << 32) | (unsigned long long)(0xFFFFFFFFu - j);
      const float f = (kv > hi || (kv > lo && s >= thr)) ? k2f(kv) : 0.0f;
      if (c == 0) o.x = f; else if (c == 1) o.y = f; else if (c == 2) o.z = f; else o.w = f;
    }
    outr[tid + TPB * i] = o;
  }
}

extern "C" void kernel_launch(void* const* d_in, const int* in_sizes, int n_in,
                              void* d_out, int out_size, void* d_ws, size_t ws_size,
                              hipStream_t stream) {
  const float* x = (const float*)d_in[0];
  const int* kptr = (const int*)d_in[1];
  float* out = (float*)d_out;
  const int B = in_sizes[0] / DCOLS;
  hipLaunchKernelGGL(topk_mask_kernel, dim3(B), dim3(TPB), 0, stream, x, kptr, out);
}

// Round 2
// 74.074 us; speedup vs baseline: 2.6303x; 2.6303x over previous
//
#include <hip/hip_runtime.h>
#include <stdint.h>

typedef unsigned long long ull;
typedef float f32x4 __attribute__((ext_vector_type(4)));

#define DCOLS 16384
#define TPB 512
#define NV 8            // float4 per thread (32 elements)
#define NB 17
#define TAILCAP 320     // ~175 expected tail elems, 320 is >10 sigma
#define BANDCAP 320

// Bin boundaries around the 64th-of-16384 N(0,1) order statistic (~2.66).
__device__ __constant__ float BNDS[NB] = {
    2.30f, 2.35f, 2.40f, 2.45f, 2.50f, 2.55f, 2.60f, 2.65f,
    2.70f, 2.75f, 2.80f, 2.85f, 2.90f, 2.95f, 3.00f, 3.05f, 3.10f};

// Monotone bijection float -> uint32 (order preserving, non-NaN).
__device__ __forceinline__ uint32_t f2k(float f) {
  uint32_t u = __float_as_uint(f);
  return u ^ (uint32_t)(((int32_t)u >> 31) | (int32_t)0x80000000);
}
__device__ __forceinline__ float k2f(uint32_t kv) {
  uint32_t u = (kv & 0x80000000u) ? (kv ^ 0x80000000u) : ~kv;
  return __uint_as_float(u);
}

__global__ void __launch_bounds__(TPB) topk_mask_kernel(
    const float* __restrict__ x, const int* __restrict__ kptr,
    float* __restrict__ out) {
  const int tid = threadIdx.x;
  const unsigned k = (unsigned)(*kptr);
  const size_t rowoff = (size_t)blockIdx.x * (size_t)DCOLS;
  const f32x4* xr = reinterpret_cast<const f32x4*>(x + rowoff);
  f32x4* outr = reinterpret_cast<f32x4*>(out + rowoff);

  __shared__ unsigned hist[NB];
  __shared__ float tf[TAILCAP];
  __shared__ unsigned tj[TAILCAP];
  __shared__ ull bsv[BANDCAP];
  __shared__ unsigned ctl[8];  // 0=tailCnt 1=bandCnt 2=loK 3=hiK 4=ghi 6=eqc 7=fb
  __shared__ ull thrSv_s;

  if (tid < NB) hist[tid] = 0u;
  if (tid < 8) ctl[tid] = 0u;
  __syncthreads();

  if (k == 0u) {  // degenerate: nothing kept (uniform across block)
    f32x4 z = {0.f, 0.f, 0.f, 0.f};
#pragma unroll
    for (int i = 0; i < NV; ++i) __builtin_nontemporal_store(z, &outr[tid + TPB * i]);
    return;
  }

  // ---- Pass 1: load row into registers; collect tail (f > BNDS[0]) in LDS ----
  f32x4 v[NV];
#pragma unroll
  for (int i = 0; i < NV; ++i) v[i] = xr[tid + TPB * i];

  const unsigned jbase = 4u * (unsigned)tid;
  const float b0 = BNDS[0];
#pragma unroll
  for (int i = 0; i < NV; ++i) {
#pragma unroll
    for (int c = 0; c < 4; ++c) {
      float f = (c == 0) ? v[i].x : (c == 1) ? v[i].y : (c == 2) ? v[i].z : v[i].w;
      if (f > b0) {
        unsigned pos = atomicAdd(&ctl[0], 1u);
        if (pos < TAILCAP) { tf[pos] = f; tj[pos] = jbase + (unsigned)(2048 * i + c); }
      }
    }
  }
  __syncthreads();
  const unsigned mtail = ctl[0];

  // ---- Histogram the tail (from LDS, exact bin = #boundaries exceeded) ----
  if (mtail <= (unsigned)TAILCAP && tid < (int)mtail) {
    float f = tf[tid];
    int b = (int)((f - b0) * 20.0f);        // approx bin, off by <=1
    if (b > NB - 1) b = NB - 1;
    if (f <= BNDS[b]) --b;                  // exact correction
    else if (b < NB - 1 && f > BNDS[b + 1]) ++b;
    atomicAdd(&hist[b], 1u);
  }
  __syncthreads();

  // ---- Thread 0: pick bracket bin (BNDS[j], BNDS[j+1]] with g(j) >= k > g(j+1) ----
  if (tid == 0) {
    unsigned gnext = 0, gj = 0;
    int jstar = -1;
    for (int j = NB - 1; j >= 0; --j) {
      gj = gnext + hist[j];
      if (gj >= k) { jstar = j; break; }
      gnext = gj;
    }
    unsigned fbf = (mtail > (unsigned)TAILCAP) || (jstar < 0) ||
                   (jstar >= 0 && (gj - gnext) > (unsigned)BANDCAP);
    if (!fbf) {
      ctl[2] = f2k(BNDS[jstar]);
      ctl[3] = (jstar == NB - 1) ? 0xFFFFFFFFu : f2k(BNDS[jstar + 1]);
      ctl[4] = gnext;  // ghi = count strictly above bracket
    }
    ctl[7] = fbf;
  }
  __syncthreads();

  unsigned ghi_use;
  if (ctl[7] == 0u) {
    // ---- Fast path: compact bracket candidates from the LDS tail ----
    ghi_use = ctl[4];
    const unsigned loK = ctl[2], hiK = ctl[3];
    if (tid < (int)mtail) {
      uint32_t kv = f2k(tf[tid]);
      if (kv > loK && kv <= hiK) {
        unsigned pos = atomicAdd(&ctl[1], 1u);
        bsv[pos] = ((ull)kv << 32) | (ull)(0xFFFFFFFFu - tj[tid]);
      }
    }
  } else {
    // ---- Generic fallback: key-space bisection over register data ----
    unsigned lo = 0u, hi = 0xFFFFFFFFu, glo = (unsigned)DCOLS, ghi = 0u;
    for (int it = 0; it < 34; ++it) {
      if ((glo - ghi) <= (unsigned)BANDCAP || (hi - lo) <= 1u) break;
      unsigned mid = lo + ((hi - lo) >> 1);
      if (tid == 0) ctl[1] = 0u;
      __syncthreads();
      unsigned c2 = 0;
#pragma unroll
      for (int i = 0; i < NV; ++i) {
        c2 += (f2k(v[i].x) > mid) ? 1u : 0u;
        c2 += (f2k(v[i].y) > mid) ? 1u : 0u;
        c2 += (f2k(v[i].z) > mid) ? 1u : 0u;
        c2 += (f2k(v[i].w) > mid) ? 1u : 0u;
      }
#pragma unroll
      for (int off = 32; off > 0; off >>= 1) c2 += __shfl_down(c2, off);
      if ((tid & 63) == 0) atomicAdd(&ctl[1], c2);
      __syncthreads();
      unsigned gm = ctl[1];
      __syncthreads();
      if (gm >= k) { lo = mid; glo = gm; } else { hi = mid; ghi = gm; }
    }
    if (tid == 0) ctl[1] = 0u;
    __syncthreads();
#pragma unroll
    for (int i = 0; i < NV; ++i) {
#pragma unroll
      for (int c = 0; c < 4; ++c) {
        float f = (c == 0) ? v[i].x : (c == 1) ? v[i].y : (c == 2) ? v[i].z : v[i].w;
        uint32_t kv = f2k(f);
        if (kv > lo && kv <= hi) {
          unsigned pos = atomicAdd(&ctl[1], 1u);
          if (pos < (unsigned)BANDCAP)
            bsv[pos] = ((ull)kv << 32) |
                       (ull)(0xFFFFFFFFu - (jbase + (unsigned)(2048 * i + c)));
        }
      }
    }
    ghi_use = ghi;
  }
  __syncthreads();
  const unsigned mband = (ctl[1] < (unsigned)BANDCAP) ? ctl[1] : (unsigned)BANDCAP;
  const unsigned r = k - ghi_use;  // 1-based rank within band

  // ---- Rank-by-count over the band (~10 candidates); also count key ties ----
  if (tid < (int)mband) {
    ull a = bsv[tid];
    unsigned cnt = 0, eq = 0;
    for (unsigned j2 = 0; j2 < mband; ++j2) {
      ull b2 = bsv[j2];
      cnt += (b2 > a) ? 1u : 0u;
      eq += ((unsigned)(b2 >> 32) == (unsigned)(a >> 32)) ? 1u : 0u;
    }
    if (cnt == r - 1u) { thrSv_s = a; ctl[6] = eq; }
  }
  __syncthreads();

  const ull thr = thrSv_s;
  const float thrF = k2f((uint32_t)(thr >> 32));

  // ---- Write pass from registers ----
  if (ctl[6] == 1u) {
    // Threshold value unique in row: keep iff f >= thrF (one compare).
#pragma unroll
    for (int i = 0; i < NV; ++i) {
      f32x4 o;
      o.x = (v[i].x >= thrF) ? v[i].x : 0.0f;
      o.y = (v[i].y >= thrF) ? v[i].y : 0.0f;
      o.z = (v[i].z >= thrF) ? v[i].z : 0.0f;
      o.w = (v[i].w >= thrF) ? v[i].w : 0.0f;
      __builtin_nontemporal_store(o, &outr[tid + TPB * i]);
    }
  } else {
    // Exact index tie-break at the threshold value (lower index wins).
    const unsigned thrIdx = 0xFFFFFFFFu - (unsigned)(thr & 0xFFFFFFFFull);
#pragma unroll
    for (int i = 0; i < NV; ++i) {
      f32x4 o;
#pragma unroll
      for (int c = 0; c < 4; ++c) {
        float f = (c == 0) ? v[i].x : (c == 1) ? v[i].y : (c == 2) ? v[i].z : v[i].w;
        unsigned jj = jbase + (unsigned)(2048 * i + c);
        float g = (f > thrF || (f == thrF && jj <= thrIdx)) ? f : 0.0f;
        if (c == 0) o.x = g; else if (c == 1) o.y = g; else if (c == 2) o.z = g; else o.w = g;
      }
      __builtin_nontemporal_store(o, &outr[tid + TPB * i]);
    }
  }
}

extern "C" void kernel_launch(void* const* d_in, const int* in_sizes, int n_in,
                              void* d_out, int out_size, void* d_ws, size_t ws_size,
                              hipStream_t stream) {
  const float* x = (const float*)d_in[0];
  const int* kptr = (const int*)d_in[1];
  float* out = (float*)d_out;
  const int B = in_sizes[0] / DCOLS;
  hipLaunchKernelGGL(topk_mask_kernel, dim3(B), dim3(TPB), 0, stream, x, kptr, out);
}